// Round 3
// baseline (1580.491 us; speedup 1.0000x reference)
//
#include <hip/hip_runtime.h>

// Cvxpy_81174881894666: batched dual ascent
//   per batch b: 100 iters of
//     z = a^T lam;  y = sigmoid(-(c+z));  g = a y + b;  lam = max(lam+0.05 g, 0)
//   output y = sigmoid(-(c + a^T lam_final)), status = zeros(int32)
//
// Design: 1 block (256 thr) per batch element. a[128][256] lives in registers:
// thread (tc=tid>>4, tr=tid&15) owns rows [tr*8, tr*8+8) x cols [tc*16, tc*16+16)
// = 128 VGPRs. Two cross-thread reductions per iter go through small LDS
// buffers (padded strides to keep bank conflicts <=4-way). 4 barriers/iter;
// __launch_bounds__(256,2) for 2 blocks/CU so barriers overlap across blocks.

#define BB 2048
#define MM 128
#define NN 256
#define NITER 100
#define STEP_ 0.05f

__global__ __launch_bounds__(256, 2) void cvx_dual_ascent(
    const float* __restrict__ A,
    const float* __restrict__ Bv,
    const float* __restrict__ C,
    float* __restrict__ out)
{
    const int bi  = blockIdx.x;
    const int tid = threadIdx.x;
    const int tc  = tid >> 4;   // 0..15 column group
    const int tr  = tid & 15;   // 0..15 row group
    const int m0  = tr * 8;     // first of my 8 rows
    const int n0  = tc * 16;    // first of my 16 cols

    // padded LDS (strides multiple of 4 floats for b128 alignment)
    __shared__ float zp_s[16][260];  // z partials: [tr][n]
    __shared__ float y_s[NN];
    __shared__ float gs[16][132];    // g partials: [tc][m]
    __shared__ float lam_s[MM];

    // ---- load my a-tile into registers (read once from HBM) ----
    const float* Ab = A + (size_t)bi * (MM * NN);
    float4 areg[8][4];
    #pragma unroll
    for (int i = 0; i < 8; ++i) {
        const float* rowp = Ab + (m0 + i) * NN + n0;
        #pragma unroll
        for (int j = 0; j < 4; ++j)
            areg[i][j] = *reinterpret_cast<const float4*>(rowp + 4 * j);
    }
    const float c_r   = C[bi * NN + tid];        // c for col tid (P2 owner)
    const int   r_row = tid >> 1;                // P4: 2 threads per row
    const int   half  = tid & 1;
    const float b_r   = half ? 0.f : Bv[bi * MM + r_row];
    float lam_r = 0.f;                            // lam[r_row], kept by pair

    if (tid < MM) lam_s[tid] = 0.f;
    __syncthreads();

    for (int it = 0; it <= NITER; ++it) {
        // ---- P1: z partials over my 8 rows, 16 cols ----
        float lamv[8];
        #pragma unroll
        for (int i = 0; i < 8; i += 4) {
            float4 lv = *reinterpret_cast<const float4*>(&lam_s[m0 + i]);
            lamv[i] = lv.x; lamv[i+1] = lv.y; lamv[i+2] = lv.z; lamv[i+3] = lv.w;
        }
        float zp[16];
        #pragma unroll
        for (int j = 0; j < 16; ++j) zp[j] = 0.f;
        #pragma unroll
        for (int i = 0; i < 8; ++i) {
            #pragma unroll
            for (int j = 0; j < 4; ++j) {
                zp[4*j+0] = fmaf(areg[i][j].x, lamv[i], zp[4*j+0]);
                zp[4*j+1] = fmaf(areg[i][j].y, lamv[i], zp[4*j+1]);
                zp[4*j+2] = fmaf(areg[i][j].z, lamv[i], zp[4*j+2]);
                zp[4*j+3] = fmaf(areg[i][j].w, lamv[i], zp[4*j+3]);
            }
        }
        #pragma unroll
        for (int j = 0; j < 4; ++j) {
            *reinterpret_cast<float4*>(&zp_s[tr][n0 + 4*j]) =
                make_float4(zp[4*j], zp[4*j+1], zp[4*j+2], zp[4*j+3]);
        }
        __syncthreads();  // B1

        // ---- P2: reduce z over tr; thread tid owns col n=tid ----
        float z = 0.f;
        #pragma unroll
        for (int i = 0; i < 16; ++i) z += zp_s[i][tid];
        const float x = c_r + z;
        const float y = 1.0f / (1.0f + expf(x));  // sigmoid(-(c+z)), stable

        if (it == NITER) {                         // final output (uniform)
            out[(size_t)bi * NN + tid] = y;
            break;
        }
        y_s[tid] = y;
        __syncthreads();  // B2

        // ---- P3: g partials over my 16 cols ----
        float yv[16];
        #pragma unroll
        for (int j = 0; j < 4; ++j) {
            float4 v = *reinterpret_cast<const float4*>(&y_s[n0 + 4*j]);
            yv[4*j] = v.x; yv[4*j+1] = v.y; yv[4*j+2] = v.z; yv[4*j+3] = v.w;
        }
        #pragma unroll
        for (int i = 0; i < 8; i += 4) {
            float4 g4;
            float* gp = &g4.x;
            #pragma unroll
            for (int k = 0; k < 4; ++k) {
                float acc = 0.f;
                #pragma unroll
                for (int j = 0; j < 4; ++j) {
                    acc = fmaf(areg[i+k][j].x, yv[4*j+0], acc);
                    acc = fmaf(areg[i+k][j].y, yv[4*j+1], acc);
                    acc = fmaf(areg[i+k][j].z, yv[4*j+2], acc);
                    acc = fmaf(areg[i+k][j].w, yv[4*j+3], acc);
                }
                gp[k] = acc;
            }
            *reinterpret_cast<float4*>(&gs[tc][m0 + i]) = g4;
        }
        __syncthreads();  // B3

        // ---- P4: reduce g over tc (2 threads/row, 8 partials each) ----
        float p = b_r;
        #pragma unroll
        for (int t = 0; t < 8; ++t) p += gs[half * 8 + t][r_row];
        p += __shfl_xor(p, 1);                    // pair-sum -> full g + b
        lam_r = fmaxf(fmaf(STEP_, p, lam_r), 0.f);
        if (!half) lam_s[r_row] = lam_r;
        __syncthreads();  // B4
    }

    if (tid == 0) out[(size_t)BB * NN + bi] = 0.0f;  // status[bi] = 0 (int32 bits)
}

extern "C" void kernel_launch(void* const* d_in, const int* in_sizes, int n_in,
                              void* d_out, int out_size, void* d_ws, size_t ws_size,
                              hipStream_t stream) {
    const float* A  = (const float*)d_in[0];  // [2048,128,256]
    const float* Bv = (const float*)d_in[1];  // [2048,128]
    const float* C  = (const float*)d_in[2];  // [2048,256]
    float* out = (float*)d_out;               // y [2048,256] f32 ++ status [2048]

    cvx_dual_ascent<<<dim3(BB), dim3(256), 0, stream>>>(A, Bv, C, out);
}